// Round 2
// baseline (666.037 us; speedup 1.0000x reference)
//
#include <hip/hip_runtime.h>

// Problem constants
constexpr int B_  = 32;    // batch
constexpr int C_  = 512;   // input channels
constexpr int F_  = 96;    // features
constexpr int P_  = 512;   // D*H*W spatial positions (8*8*8)
constexpr int NTH = 384;   // 4 batch-groups x 96 f-lanes
constexpr int BPG = 8;     // batches per group (32/4)

__device__ __forceinline__ unsigned short f2bf(float v) {
    unsigned int u = __float_as_uint(v);
    unsigned int r = (u + 0x7FFFu + ((u >> 16) & 1u)) >> 16;  // RNE
    return (unsigned short)r;
}
__device__ __forceinline__ float bf2f(unsigned short v) {
    return __uint_as_float(((unsigned int)v) << 16);
}

__global__ __launch_bounds__(NTH, 3) void lstm3d_fused(
    const float* __restrict__ x,    // (32,512)
    const float* __restrict__ h_t,  // (32,512,96)
    const float* __restrict__ s_t,  // (32,512,96)
    const float* __restrict__ Wf,   // (512,512,96)
    const float* __restrict__ Wi,
    const float* __restrict__ Ws,
    const float* __restrict__ Uf,   // (27,96,96)
    const float* __restrict__ Ui,
    const float* __restrict__ Us,
    const float* __restrict__ bf,   // (96)
    const float* __restrict__ bi,
    const float* __restrict__ bs,
    float* __restrict__ out)        // h (32,512,96) then s (32,512,96)
{
    __shared__ __align__(16) unsigned char lds_raw[B_*C_*2 + B_*F_*4]; // 32KB bf16 x + 12KB f32 h-slab
    unsigned short* s_in = (unsigned short*)lds_raw;     // x as bf16, [32][512]
    float*          s_h  = (float*)(lds_raw + B_*C_*2);  // h-neighbor slab, [32][96]

    const int p   = blockIdx.x;
    const int d   = p >> 6;
    const int hh  = (p >> 3) & 7;
    const int ww  = p & 7;
    const int tid = threadIdx.x;
    const int f   = tid % F_;
    const int bg  = tid / F_;     // 0..3
    const int b0  = bg * BPG;

    // ---- stage inputs (32x512 fp32 -> bf16) into LDS ----
    {
        const float4* x4 = (const float4*)x;
        ushort4* s4 = (ushort4*)s_in;
        for (int i = tid; i < B_ * C_ / 4; i += NTH) {
            float4 v = x4[i];
            ushort4 u;
            u.x = f2bf(v.x); u.y = f2bf(v.y); u.z = f2bf(v.z); u.w = f2bf(v.w);
            s4[i] = u;
        }
    }
    __syncthreads();

    // ---- input projection: af/ai/as_[j] = sum_c x[b0+j,c] * Wg[p,c,f] ----
    const size_t wbase = (size_t)p * C_ * F_;
    const float* __restrict__ Wfp = Wf + wbase;
    const float* __restrict__ Wip = Wi + wbase;
    const float* __restrict__ Wsp = Ws + wbase;

    float af[BPG], ai[BPG], as_[BPG];
    #pragma unroll
    for (int j = 0; j < BPG; ++j) { af[j] = 0.f; ai[j] = 0.f; as_[j] = 0.f; }

    for (int c = 0; c < C_; c += 4) {
        float xs[BPG][4];
        #pragma unroll
        for (int j = 0; j < BPG; ++j) {
            ushort4 uv = *(const ushort4*)&s_in[(b0 + j) * C_ + c];
            xs[j][0] = bf2f(uv.x); xs[j][1] = bf2f(uv.y);
            xs[j][2] = bf2f(uv.z); xs[j][3] = bf2f(uv.w);
        }
        #pragma unroll
        for (int cc = 0; cc < 4; ++cc) {
            const float wfv = Wfp[(c + cc) * F_ + f];
            const float wiv = Wip[(c + cc) * F_ + f];
            const float wsv = Wsp[(c + cc) * F_ + f];
            #pragma unroll
            for (int j = 0; j < BPG; ++j) {
                af[j]  = fmaf(xs[j][cc], wfv, af[j]);
                ai[j]  = fmaf(xs[j][cc], wiv, ai[j]);
                as_[j] = fmaf(xs[j][cc], wsv, as_[j]);
            }
        }
    }

    // ---- 3D conv (SAME, zero pad): cf/cig/cs[j] += h[b, neighbor, ci] * Ug[k, ci, f] ----
    float cf[BPG], cig[BPG], cs[BPG];
    #pragma unroll
    for (int j = 0; j < BPG; ++j) { cf[j] = 0.f; cig[j] = 0.f; cs[j] = 0.f; }

    for (int kd = 0; kd < 3; ++kd) {
        const int nd = d + kd - 1;
        if ((unsigned)nd >= 8u) continue;
        for (int kh = 0; kh < 3; ++kh) {
            const int nh = hh + kh - 1;
            if ((unsigned)nh >= 8u) continue;
            for (int kw = 0; kw < 3; ++kw) {
                const int nw = ww + kw - 1;
                if ((unsigned)nw >= 8u) continue;   // uniform across block (depends on blockIdx only)
                const int np = (nd << 6) + (nh << 3) + nw;
                const int k  = (kd * 3 + kh) * 3 + kw;

                __syncthreads();   // protect s_h from previous iteration's readers
                {
                    const float4* h4 = (const float4*)h_t;
                    float4* s4 = (float4*)s_h;
                    for (int i = tid; i < B_ * F_ / 4; i += NTH) {
                        const int b2 = i / (F_ / 4);
                        const int r  = i % (F_ / 4);
                        s4[i] = h4[(size_t)(b2 * P_ + np) * (F_ / 4) + r];
                    }
                }
                __syncthreads();

                const float* __restrict__ Ufk = Uf + (size_t)k * F_ * F_;
                const float* __restrict__ Uik = Ui + (size_t)k * F_ * F_;
                const float* __restrict__ Usk = Us + (size_t)k * F_ * F_;

                for (int ci = 0; ci < F_; ci += 4) {
                    float hs[BPG][4];
                    #pragma unroll
                    for (int j = 0; j < BPG; ++j) {
                        float4 t = *(const float4*)&s_h[(b0 + j) * F_ + ci];
                        hs[j][0] = t.x; hs[j][1] = t.y; hs[j][2] = t.z; hs[j][3] = t.w;
                    }
                    #pragma unroll
                    for (int cc = 0; cc < 4; ++cc) {
                        const float ufv = Ufk[(ci + cc) * F_ + f];
                        const float uiv = Uik[(ci + cc) * F_ + f];
                        const float usv = Usk[(ci + cc) * F_ + f];
                        #pragma unroll
                        for (int j = 0; j < BPG; ++j) {
                            cf[j]  = fmaf(hs[j][cc], ufv, cf[j]);
                            cig[j] = fmaf(hs[j][cc], uiv, cig[j]);
                            cs[j]  = fmaf(hs[j][cc], usv, cs[j]);
                        }
                    }
                }
            }
        }
    }

    // ---- epilogue: gates, state update, writes ----
    const float bfv = bf[f], biv = bi[f], bsv = bs[f];
    float* __restrict__ out_h = out;
    float* __restrict__ out_s = out + (size_t)B_ * P_ * F_;

    #pragma unroll
    for (int j = 0; j < BPG; ++j) {
        const size_t idx = (size_t)((b0 + j) * P_ + p) * F_ + f;
        const float gf = af[j]  + cf[j]  + bfv;
        const float gi = ai[j]  + cig[j] + biv;
        const float gs = as_[j] + cs[j]  + bsv;
        const float fg = fminf(fmaxf(0.2f * gf + 0.5f, 0.f), 1.f);
        const float ig = fminf(fmaxf(0.2f * gi + 0.5f, 0.f), 1.f);
        const float sv = fg * s_t[idx] + ig * tanhf(gs);
        out_h[idx] = tanhf(sv);
        out_s[idx] = sv;
    }
}

extern "C" void kernel_launch(void* const* d_in, const int* in_sizes, int n_in,
                              void* d_out, int out_size, void* d_ws, size_t ws_size,
                              hipStream_t stream) {
    const float* x   = (const float*)d_in[0];
    const float* h_t = (const float*)d_in[1];
    const float* s_t = (const float*)d_in[2];
    const float* Wf  = (const float*)d_in[3];
    const float* Wi  = (const float*)d_in[4];
    const float* Ws  = (const float*)d_in[5];
    const float* Uf  = (const float*)d_in[6];
    const float* Ui  = (const float*)d_in[7];
    const float* Us  = (const float*)d_in[8];
    const float* bf  = (const float*)d_in[9];
    const float* bi  = (const float*)d_in[10];
    const float* bs  = (const float*)d_in[11];
    float* out = (float*)d_out;

    hipLaunchKernelGGL(lstm3d_fused, dim3(P_), dim3(NTH), 0, stream,
                       x, h_t, s_t, Wf, Wi, Ws, Uf, Ui, Us, bf, bi, bs, out);
}

// Round 3
// 110.171 us; speedup vs baseline: 6.0455x; 6.0455x over previous
//
#include <hip/hip_runtime.h>

typedef __attribute__((ext_vector_type(8))) short short8;
typedef __attribute__((ext_vector_type(4))) float f32x4;

constexpr int B_ = 32, C_ = 512, F_ = 96, P_ = 512;
constexpr int NTH = 768;          // 12 waves
constexpr int GRID = 256;         // 2 positions per block
constexpr size_t OUT_HALF = (size_t)B_ * P_ * F_;

// ---- workspace layout (bytes) ----
constexpr size_t WS_U  = 0;                       // [27 tap][3 g][96 f][52 u32] bf16 pairs
constexpr size_t WS_U_SZ = 27ull * 3 * 96 * 52 * 4;   // 1,617,408
constexpr size_t WS_H  = WS_U + WS_U_SZ;          // [32 b][512 p][96 ci] bf16
constexpr size_t WS_H_SZ = 32ull * 512 * 96 * 2;      // 3,145,728
constexpr size_t WS_X  = WS_H + WS_H_SZ;          // [32 b][512 c] bf16
constexpr size_t WS_X_SZ = 32ull * 512 * 2;           // 32,768
constexpr size_t WS_END = WS_X + WS_X_SZ;             // 4,795,904

// ---- dynamic LDS layout (bytes) ----
constexpr int SH_OFF = 0;          // conv h: 2 bufs x [64 row][208 B]
constexpr int SH_BUF = 64 * 208;                  // 13,312
constexpr int SU_OFF = SH_OFF + 2 * SH_BUF;       // 26,624: conv U: 2 bufs x [3 g][96 f][208 B]
constexpr int SU_BUF = 3 * 96 * 208;              // 59,904
constexpr int LDS_TOTAL = SU_OFF + 2 * SU_BUF;    // 146,432
constexpr int SX_OFF = 0;          // proj x: [32 row][1040 B] = 33,280
constexpr int SW_OFF = 33280;      // proj W: 2 bufs x 6 slabs x [96 f][80 B]
constexpr int SW_BUF = 6 * 96 * 80;               // 46,080
constexpr int PRE_OFF = 0;         // merge: [2 m][3 g][32 r][96 f] f32 = 73,728

__device__ __forceinline__ unsigned short f2bf(float v) {
    unsigned int u = __float_as_uint(v);
    unsigned int r = (u + 0x7FFFu + ((u >> 16) & 1u)) >> 16;  // RNE
    return (unsigned short)r;
}
__device__ __forceinline__ unsigned pack2bf(float a, float b) {
    return (unsigned)f2bf(a) | ((unsigned)f2bf(b) << 16);
}
__device__ __forceinline__ float bf2f(unsigned short v) {
    return __uint_as_float(((unsigned int)v) << 16);
}

// ================= prep kernels =================
__global__ __launch_bounds__(256) void prep_u(const float* __restrict__ Uf,
                                              const float* __restrict__ Ui,
                                              const float* __restrict__ Us,
                                              unsigned char* __restrict__ wsb) {
    __shared__ float s32[96 * 97];
    const int t = blockIdx.x / 3, g = blockIdx.x % 3;
    const float* U = (g == 0 ? Uf : (g == 1 ? Ui : Us)) + (size_t)t * 9216;
    const int tid = threadIdx.x;
    #pragma unroll
    for (int j = 0; j < 36; ++j) {              // 9216 = 36*256
        int idx = j * 256 + tid;
        int ci = idx / 96, f = idx % 96;
        s32[ci * 97 + f] = U[idx];
    }
    __syncthreads();
    unsigned* dst = (unsigned*)(wsb + WS_U) + (size_t)(t * 3 + g) * 4992;
    #pragma unroll
    for (int j = 0; j < 20; ++j) {
        int o = j * 256 + tid;
        if (o < 4992) {                          // 96 f * 52 u32
            int f = o / 52, qq = o % 52;
            unsigned pk = 0u;
            if (qq < 48) pk = pack2bf(s32[(2 * qq) * 97 + f], s32[(2 * qq + 1) * 97 + f]);
            dst[o] = pk;
        }
    }
}

__global__ __launch_bounds__(256) void prep_hx(const float* __restrict__ h_t,
                                               const float* __restrict__ x,
                                               unsigned char* __restrict__ wsb) {
    unsigned* wh = (unsigned*)(wsb + WS_H);
    unsigned* wx = (unsigned*)(wsb + WS_X);
    const int tid = threadIdx.x;
    #pragma unroll
    for (int j = 0; j < 4; ++j) {
        size_t u = (size_t)blockIdx.x * 1024 + j * 256 + tid;
        if (u < 786432) {                        // h_t pairs
            float2 v = *(const float2*)(h_t + 2 * u);
            wh[u] = pack2bf(v.x, v.y);
        } else if (u < 794624) {                 // x pairs
            size_t v_ = u - 786432;
            float2 v = *(const float2*)(x + 2 * v_);
            wx[v_] = pack2bf(v.x, v.y);
        }
    }
}

// ================= main fused kernel =================
__global__ __launch_bounds__(NTH, 3) void lstm3d_main(
    const float* __restrict__ Wf, const float* __restrict__ Wi, const float* __restrict__ Ws,
    const float* __restrict__ s_t,
    const float* __restrict__ bfp, const float* __restrict__ bip, const float* __restrict__ bsp,
    const unsigned char* __restrict__ wsb, float* __restrict__ out)
{
    extern __shared__ char sm[];
    const int tid  = threadIdx.x;
    const int lane = tid & 63;
    const int wv   = tid >> 6;            // 0..11
    const int kp   = (wv >= 6) ? 1 : 0;   // K-parity
    const int w6   = kp ? wv - 6 : wv;
    const int g    = w6 >> 1;             // gate 0..2
    const int m    = w6 & 1;              // position half 0/1
    const int l15  = lane & 15, l4 = lane >> 4;

    const int bid = blockIdx.x;
    const int w0  = (bid & 3) * 2;
    const int dh  = bid >> 2;
    const int dd  = dh >> 3, hh = dh & 7;
    const int p0  = dd * 64 + hh * 8 + w0;

    const unsigned char* wh8 = wsb + WS_H;
    const unsigned char* wu8 = wsb + WS_U;
    const unsigned char* wx8 = wsb + WS_X;

    f32x4 acc[2][6];
    #pragma unroll
    for (int a = 0; a < 2; ++a)
        #pragma unroll
        for (int b = 0; b < 6; ++b) acc[a][b] = (f32x4){0.f, 0.f, 0.f, 0.f};

    // staging roles
    const int hrow = tid / 12;            // 0..63
    const int hgq  = tid % 12;            // 16B granule within 192B row
    const int hhalf = hrow >> 5, hb = hrow & 31;

    auto tap_info = [&](int kt, int& np0, int& np1, int& a0, int& a1) {
        int kd = kt / 9, kh = (kt / 3) % 3, kw = kt % 3;
        int nd = dd + kd - 1, nh = hh + kh - 1;
        int nwA = w0 + kw - 1, nwB = nwA + 1;
        int ok = ((unsigned)nd < 8u) && ((unsigned)nh < 8u);
        a0 = ok && ((unsigned)nwA < 8u);
        a1 = ok && ((unsigned)nwB < 8u);
        np0 = nd * 64 + nh * 8 + nwA;
        np1 = nd * 64 + nh * 8 + nwB;
    };

    // ---------------- conv phase ----------------
    int kt = 0, np0 = 0, np1 = 0, a0 = 0, a1 = 0;
    for (; kt < 27; ++kt) { tap_info(kt, np0, np1, a0, a1); if (a0 | a1) break; }

    {   // prologue: stage buf0
        uint4 hv = {0u, 0u, 0u, 0u};
        int np = hhalf ? np1 : np0;
        int av = hhalf ? a1 : a0;
        if (av) hv = *(const uint4*)(wh8 + (size_t)hb * 98304 + np * 192 + hgq * 16);
        *(uint4*)(sm + SH_OFF + hrow * 208 + hgq * 16) = hv;
        #pragma unroll
        for (int j = 0; j < 5; ++j) {
            int gi = j * 768 + tid;
            if (gi < 3744) {
                uint4 uv = *(const uint4*)(wu8 + (size_t)kt * 59904 + gi * 16);
                *(uint4*)(sm + SU_OFF + gi * 16) = uv;
            }
        }
    }
    __syncthreads();

    int buf = 0, actIdx = 0;
    while (kt < 27) {
        // find next active tap
        int ktn = kt + 1, np0n = 0, np1n = 0, a0n = 0, a1n = 0;
        for (; ktn < 27; ++ktn) { tap_info(ktn, np0n, np1n, a0n, a1n); if (a0n | a1n) break; }
        const bool havenext = (ktn < 27);

        // issue next-tap loads into registers (fly during MFMA)
        uint4 hv = {0u, 0u, 0u, 0u};
        uint4 uv0, uv1, uv2, uv3, uv4;
        if (havenext) {
            int np = hhalf ? np1n : np0n;
            int av = hhalf ? a1n : a0n;
            if (av) hv = *(const uint4*)(wh8 + (size_t)hb * 98304 + np * 192 + hgq * 16);
            const unsigned char* ub = wu8 + (size_t)ktn * 59904;
            uv0 = *(const uint4*)(ub + (0 * 768 + tid) * 16);
            uv1 = *(const uint4*)(ub + (1 * 768 + tid) * 16);
            uv2 = *(const uint4*)(ub + (2 * 768 + tid) * 16);
            uv3 = *(const uint4*)(ub + (3 * 768 + tid) * 16);
            if (4 * 768 + tid < 3744) uv4 = *(const uint4*)(ub + (4 * 768 + tid) * 16);
        }

        // MFMA on current buffer, tap kt
        {
            const char* shb = sm + SH_OFF + buf * SH_BUF;
            const char* sub = sm + SU_OFF + buf * SU_BUF + g * 19968;
            #pragma unroll
            for (int ks = 0; ks < 3; ++ks) {
                if (((actIdx * 3 + ks) & 1) != kp) continue;
                short8 afr0 = *(const short8*)(shb + (m * 32 + l15) * 208      + ks * 64 + l4 * 16);
                short8 afr1 = *(const short8*)(shb + (m * 32 + 16 + l15) * 208 + ks * 64 + l4 * 16);
                #pragma unroll
                for (int n = 0; n < 6; ++n) {
                    short8 bfr = *(const short8*)(sub + (n * 16 + l15) * 208 + ks * 64 + l4 * 16);
                    acc[0][n] = __builtin_amdgcn_mfma_f32_16x16x32_bf16(afr0, bfr, acc[0][n], 0, 0, 0);
                    acc[1][n] = __builtin_amdgcn_mfma_f32_16x16x32_bf16(afr1, bfr, acc[1][n], 0, 0, 0);
                }
            }
        }

        // write next buffer
        if (havenext) {
            *(uint4*)(sm + SH_OFF + (buf ^ 1) * SH_BUF + hrow * 208 + hgq * 16) = hv;
            char* sb = sm + SU_OFF + (buf ^ 1) * SU_BUF;
            *(uint4*)(sb + (0 * 768 + tid) * 16) = uv0;
            *(uint4*)(sb + (1 * 768 + tid) * 16) = uv1;
            *(uint4*)(sb + (2 * 768 + tid) * 16) = uv2;
            *(uint4*)(sb + (3 * 768 + tid) * 16) = uv3;
            if (4 * 768 + tid < 3744) *(uint4*)(sb + (4 * 768 + tid) * 16) = uv4;
        }
        __syncthreads();
        buf ^= 1; ++actIdx;
        kt = ktn; np0 = np0n; np1 = np1n; a0 = a0n; a1 = a1n;
    }

    // ---------------- projection phase ----------------
    // stage x (bf16) into s_x [32][1040B]
    #pragma unroll
    for (int j = 0; j < 3; ++j) {
        int gi = j * 768 + tid;
        if (gi < 2048) {
            int row = gi >> 6, gg = gi & 63;
            uint4 v = *(const uint4*)(wx8 + row * 1024 + gg * 16);
            *(uint4*)(sm + SX_OFF + row * 1040 + gg * 16) = v;
        }
    }

    // W staging role: two r values per thread
    const int rA = tid, rB = 768 + tid;           // within 1536-u32 slab
    const int qA = rA / 96, fA = rA % 96;
    const int qB = rB / 96, fB = rB % 96;

    // prologue: load+write k-step 0 into buf0
    float2 wvv[12];
    #pragma unroll
    for (int j = 0; j < 12; ++j) {
        const int s  = j >> 1;                    // slab 0..5
        const int sg = s >> 1;                    // gate (compile-time)
        const int sp = s & 1;                     // position
        const int q  = (j & 1) ? qB : qA;
        const int f  = (j & 1) ? fB : fA;
        const float* W = (sg == 0) ? Wf : ((sg == 1) ? Wi : Ws);
        size_t base = ((size_t)(p0 + sp) * 512 + 2 * q) * 96 + f;
        wvv[j].x = W[base];
        wvv[j].y = W[base + 96];
    }
    #pragma unroll
    for (int j = 0; j < 12; ++j) {
        const int s = j >> 1;
        const int q = (j & 1) ? qB : qA;
        const int f = (j & 1) ? fB : fA;
        *(unsigned*)(sm + SW_OFF + s * 7680 + f * 80 + q * 4) = pack2bf(wvv[j].x, wvv[j].y);
    }
    __syncthreads();

    buf = 0;
    for (int ks = 0; ks < 16; ++ks) {
        const bool havenext = (ks + 1) < 16;
        if (havenext) {
            const int c0n = (ks + 1) * 32;
            #pragma unroll
            for (int j = 0; j < 12; ++j) {
                const int s  = j >> 1;
                const int sg = s >> 1;
                const int sp = s & 1;
                const int q  = (j & 1) ? qB : qA;
                const int f  = (j & 1) ? fB : fA;
                const float* W = (sg == 0) ? Wf : ((sg == 1) ? Wi : Ws);
                size_t base = ((size_t)(p0 + sp) * 512 + c0n + 2 * q) * 96 + f;
                wvv[j].x = W[base];
                wvv[j].y = W[base + 96];
            }
        }

        if ((ks & 1) == kp) {
            const char* sxb = sm + SX_OFF;
            const char* swb = sm + SW_OFF + buf * SW_BUF + (g * 2 + m) * 7680;
            short8 afr0 = *(const short8*)(sxb + (l15) * 1040      + ks * 64 + l4 * 16);
            short8 afr1 = *(const short8*)(sxb + (16 + l15) * 1040 + ks * 64 + l4 * 16);
            #pragma unroll
            for (int n = 0; n < 6; ++n) {
                short8 bfr = *(const short8*)(swb + (n * 16 + l15) * 80 + l4 * 16);
                acc[0][n] = __builtin_amdgcn_mfma_f32_16x16x32_bf16(afr0, bfr, acc[0][n], 0, 0, 0);
                acc[1][n] = __builtin_amdgcn_mfma_f32_16x16x32_bf16(afr1, bfr, acc[1][n], 0, 0, 0);
            }
        }

        if (havenext) {
            #pragma unroll
            for (int j = 0; j < 12; ++j) {
                const int s = j >> 1;
                const int q = (j & 1) ? qB : qA;
                const int f = (j & 1) ? fB : fA;
                *(unsigned*)(sm + SW_OFF + (buf ^ 1) * SW_BUF + s * 7680 + f * 80 + q * 4) =
                    pack2bf(wvv[j].x, wvv[j].y);
            }
        }
        __syncthreads();
        buf ^= 1;
    }

    // ---------------- merge K-parity partials ----------------
    float* pre = (float*)(sm + PRE_OFF);
    const int preBase = (m * 3 + g) * 32 * 96;
    if (kp == 1) {
        #pragma unroll
        for (int ti = 0; ti < 2; ++ti)
            #pragma unroll
            for (int n = 0; n < 6; ++n)
                #pragma unroll
                for (int r = 0; r < 4; ++r)
                    pre[preBase + (ti * 16 + l4 * 4 + r) * 96 + n * 16 + l15] = acc[ti][n][r];
    }
    __syncthreads();
    if (kp == 0) {
        #pragma unroll
        for (int ti = 0; ti < 2; ++ti)
            #pragma unroll
            for (int n = 0; n < 6; ++n)
                #pragma unroll
                for (int r = 0; r < 4; ++r)
                    pre[preBase + (ti * 16 + l4 * 4 + r) * 96 + n * 16 + l15] += acc[ti][n][r];
    }
    __syncthreads();

    // ---------------- epilogue ----------------
    #pragma unroll
    for (int j = 0; j < 8; ++j) {
        int u  = j * 768 + tid;                  // 0..6143
        int mm = u / 3072;
        int rr = (u / 96) % 32;
        int ff = u % 96;
        float gfv = pre[((mm * 3 + 0) * 32 + rr) * 96 + ff] + bfp[ff];
        float giv = pre[((mm * 3 + 1) * 32 + rr) * 96 + ff] + bip[ff];
        float gsv = pre[((mm * 3 + 2) * 32 + rr) * 96 + ff] + bsp[ff];
        int pg = p0 + mm;
        size_t idx = ((size_t)rr * 512 + pg) * 96 + ff;
        float fg = fminf(fmaxf(0.2f * gfv + 0.5f, 0.f), 1.f);
        float ig = fminf(fmaxf(0.2f * giv + 0.5f, 0.f), 1.f);
        float sv = fg * s_t[idx] + ig * tanhf(gsv);
        out[idx] = tanhf(sv);
        out[OUT_HALF + idx] = sv;
    }
}

// ================= fp32 fallback (round-2 kernel, used if ws too small) =================
constexpr int FNTH = 384;
constexpr int FBPG = 8;
__global__ __launch_bounds__(FNTH, 3) void lstm3d_fused(
    const float* __restrict__ x, const float* __restrict__ h_t, const float* __restrict__ s_t,
    const float* __restrict__ Wf, const float* __restrict__ Wi, const float* __restrict__ Ws,
    const float* __restrict__ Uf, const float* __restrict__ Ui, const float* __restrict__ Us,
    const float* __restrict__ bf, const float* __restrict__ bi, const float* __restrict__ bs,
    float* __restrict__ out)
{
    __shared__ __align__(16) unsigned char lds_raw[B_*C_*2 + B_*F_*4];
    unsigned short* s_in = (unsigned short*)lds_raw;
    float*          s_h  = (float*)(lds_raw + B_*C_*2);
    const int p = blockIdx.x, d = p >> 6, hh = (p >> 3) & 7, ww = p & 7;
    const int tid = threadIdx.x, f = tid % F_, bg = tid / F_, b0 = bg * FBPG;
    {
        const float4* x4 = (const float4*)x;
        ushort4* s4 = (ushort4*)s_in;
        for (int i = tid; i < B_ * C_ / 4; i += FNTH) {
            float4 v = x4[i];
            ushort4 u; u.x = f2bf(v.x); u.y = f2bf(v.y); u.z = f2bf(v.z); u.w = f2bf(v.w);
            s4[i] = u;
        }
    }
    __syncthreads();
    const size_t wbase = (size_t)p * C_ * F_;
    const float* Wfp = Wf + wbase; const float* Wip = Wi + wbase; const float* Wsp = Ws + wbase;
    float af[FBPG], ai[FBPG], as_[FBPG];
    #pragma unroll
    for (int j = 0; j < FBPG; ++j) { af[j] = 0.f; ai[j] = 0.f; as_[j] = 0.f; }
    for (int c = 0; c < C_; c += 4) {
        float xs[FBPG][4];
        #pragma unroll
        for (int j = 0; j < FBPG; ++j) {
            ushort4 uv = *(const ushort4*)&s_in[(b0 + j) * C_ + c];
            xs[j][0] = bf2f(uv.x); xs[j][1] = bf2f(uv.y); xs[j][2] = bf2f(uv.z); xs[j][3] = bf2f(uv.w);
        }
        #pragma unroll
        for (int cc = 0; cc < 4; ++cc) {
            const float wfv = Wfp[(c + cc) * F_ + f], wiv = Wip[(c + cc) * F_ + f], wsv = Wsp[(c + cc) * F_ + f];
            #pragma unroll
            for (int j = 0; j < FBPG; ++j) {
                af[j] = fmaf(xs[j][cc], wfv, af[j]); ai[j] = fmaf(xs[j][cc], wiv, ai[j]); as_[j] = fmaf(xs[j][cc], wsv, as_[j]);
            }
        }
    }
    float cf[FBPG], cig[FBPG], cs[FBPG];
    #pragma unroll
    for (int j = 0; j < FBPG; ++j) { cf[j] = 0.f; cig[j] = 0.f; cs[j] = 0.f; }
    for (int kd = 0; kd < 3; ++kd) {
        const int nd = d + kd - 1; if ((unsigned)nd >= 8u) continue;
        for (int kh = 0; kh < 3; ++kh) {
            const int nh = hh + kh - 1; if ((unsigned)nh >= 8u) continue;
            for (int kw = 0; kw < 3; ++kw) {
                const int nw = ww + kw - 1; if ((unsigned)nw >= 8u) continue;
                const int np = (nd << 6) + (nh << 3) + nw, k = (kd * 3 + kh) * 3 + kw;
                __syncthreads();
                {
                    const float4* h4 = (const float4*)h_t; float4* s4 = (float4*)s_h;
                    for (int i = tid; i < B_ * F_ / 4; i += FNTH) {
                        const int b2 = i / (F_ / 4), r = i % (F_ / 4);
                        s4[i] = h4[(size_t)(b2 * P_ + np) * (F_ / 4) + r];
                    }
                }
                __syncthreads();
                const float* Ufk = Uf + (size_t)k * F_ * F_; const float* Uik = Ui + (size_t)k * F_ * F_; const float* Usk = Us + (size_t)k * F_ * F_;
                for (int ci = 0; ci < F_; ci += 4) {
                    float hs[FBPG][4];
                    #pragma unroll
                    for (int j = 0; j < FBPG; ++j) {
                        float4 t = *(const float4*)&s_h[(b0 + j) * F_ + ci];
                        hs[j][0] = t.x; hs[j][1] = t.y; hs[j][2] = t.z; hs[j][3] = t.w;
                    }
                    #pragma unroll
                    for (int cc = 0; cc < 4; ++cc) {
                        const float ufv = Ufk[(ci + cc) * F_ + f], uiv = Uik[(ci + cc) * F_ + f], usv = Usk[(ci + cc) * F_ + f];
                        #pragma unroll
                        for (int j = 0; j < FBPG; ++j) {
                            cf[j] = fmaf(hs[j][cc], ufv, cf[j]); cig[j] = fmaf(hs[j][cc], uiv, cig[j]); cs[j] = fmaf(hs[j][cc], usv, cs[j]);
                        }
                    }
                }
            }
        }
    }
    const float bfv = bf[f], biv = bi[f], bsv = bs[f];
    #pragma unroll
    for (int j = 0; j < FBPG; ++j) {
        const size_t idx = (size_t)((b0 + j) * P_ + p) * F_ + f;
        const float gf = af[j] + cf[j] + bfv, gi = ai[j] + cig[j] + biv, gs = as_[j] + cs[j] + bsv;
        const float fg = fminf(fmaxf(0.2f * gf + 0.5f, 0.f), 1.f);
        const float ig = fminf(fmaxf(0.2f * gi + 0.5f, 0.f), 1.f);
        const float sv = fg * s_t[idx] + ig * tanhf(gs);
        out[idx] = tanhf(sv);
        out[OUT_HALF + idx] = sv;
    }
}

extern "C" void kernel_launch(void* const* d_in, const int* in_sizes, int n_in,
                              void* d_out, int out_size, void* d_ws, size_t ws_size,
                              hipStream_t stream) {
    const float* x   = (const float*)d_in[0];
    const float* h_t = (const float*)d_in[1];
    const float* s_t = (const float*)d_in[2];
    const float* Wf  = (const float*)d_in[3];
    const float* Wi  = (const float*)d_in[4];
    const float* Ws  = (const float*)d_in[5];
    const float* Uf  = (const float*)d_in[6];
    const float* Ui  = (const float*)d_in[7];
    const float* Us  = (const float*)d_in[8];
    const float* bf  = (const float*)d_in[9];
    const float* bi  = (const float*)d_in[10];
    const float* bs  = (const float*)d_in[11];
    float* out = (float*)d_out;

    if (ws_size >= WS_END) {
        (void)hipFuncSetAttribute(reinterpret_cast<const void*>(lstm3d_main),
                                  hipFuncAttributeMaxDynamicSharedMemorySize, LDS_TOTAL);
        unsigned char* wsb = (unsigned char*)d_ws;
        hipLaunchKernelGGL(prep_u, dim3(81), dim3(256), 0, stream, Uf, Ui, Us, wsb);
        hipLaunchKernelGGL(prep_hx, dim3(776), dim3(256), 0, stream, h_t, x, wsb);
        hipLaunchKernelGGL(lstm3d_main, dim3(GRID), dim3(NTH), LDS_TOTAL, stream,
                           Wf, Wi, Ws, s_t, bf, bi, bs, wsb, out);
    } else {
        hipLaunchKernelGGL(lstm3d_fused, dim3(P_), dim3(FNTH), 0, stream,
                           x, h_t, s_t, Wf, Wi, Ws, Uf, Ui, Us, bf, bi, bs, out);
    }
}